// Round 1
// baseline (574.350 us; speedup 1.0000x reference)
//
#include <hip/hip_runtime.h>

#define Bx 2
#define Cx 256
#define Hx 128
#define Wx 128
#define HWx (Hx*Wx)     // 16384
#define Ox 256
#define Kx 9
#define NOFF 27         // 3*K offset-conv output channels

// ws layout (float offsets):
//   tmp   [0, 884736)            B*27*HW
//   w_t   [884736, 946944)       27*256*9 transposed to [c][oc][t]
//   stats [946944, 947008)       18*2 (max, 1/sum) padded
//   agg   [947008, 947008+8388608)

__global__ void k_zero(float* __restrict__ p, int n) {
    int i = blockIdx.x * 256 + threadIdx.x;
    if (i < n) p[i] = 0.f;
}

__global__ void k_wtr(const float* __restrict__ w_off, float* __restrict__ w_t) {
    int i = blockIdx.x * 256 + threadIdx.x;
    if (i >= NOFF * Cx * 9) return;
    int oc = i / (Cx * 9);
    int r  = i % (Cx * 9);
    int c  = r / 9;
    int t  = r % 9;
    w_t[(c * NOFF + oc) * 9 + t] = w_off[i];
}

// 3x3 conv C=256 -> 27, pad 1. Block = one image row (128 threads), grid (H, B, 4 c-chunks).
__global__ __launch_bounds__(128) void k1_offconv(
        const float* __restrict__ x, const float* __restrict__ w_t,
        const float* __restrict__ b_off, float* __restrict__ tmp) {
    int tid = threadIdx.x;            // x coordinate, 0..127
    int y   = blockIdx.x;
    int b   = blockIdx.y;
    int cc  = blockIdx.z;             // c-chunk 0..3

    __shared__ float rows[2][3][Wx + 2];   // ping-pong, halo at [0] and [129]
    if (tid < 2) {
        int e = tid * (Wx + 1);            // 0 or 129
        rows[0][0][e] = 0.f; rows[0][1][e] = 0.f; rows[0][2][e] = 0.f;
        rows[1][0][e] = 0.f; rows[1][1][e] = 0.f; rows[1][2][e] = 0.f;
    }

    float acc[NOFF];
#pragma unroll
    for (int oc = 0; oc < NOFF; oc++) acc[oc] = (cc == 0) ? b_off[oc] : 0.f;

    int c0 = cc * 64;
    for (int ci = 0; ci < 64; ci++) {
        int c = c0 + ci;
        int buf = ci & 1;
#pragma unroll
        for (int r = 0; r < 3; r++) {
            int yy = y + r - 1;
            float v = 0.f;
            if (yy >= 0 && yy < Hx) v = x[((b * Cx + c) * Hx + yy) * Wx + tid];
            rows[buf][r][tid + 1] = v;
        }
        __syncthreads();
        float t0 = rows[buf][0][tid],     t1 = rows[buf][0][tid + 1], t2 = rows[buf][0][tid + 2];
        float t3 = rows[buf][1][tid],     t4 = rows[buf][1][tid + 1], t5 = rows[buf][1][tid + 2];
        float t6 = rows[buf][2][tid],     t7 = rows[buf][2][tid + 1], t8 = rows[buf][2][tid + 2];
        const float* wc = w_t + c * (NOFF * 9);   // uniform address -> scalar loads
#pragma unroll
        for (int oc = 0; oc < NOFF; oc++) {
            acc[oc] += wc[oc * 9 + 0] * t0 + wc[oc * 9 + 1] * t1 + wc[oc * 9 + 2] * t2
                     + wc[oc * 9 + 3] * t3 + wc[oc * 9 + 4] * t4 + wc[oc * 9 + 5] * t5
                     + wc[oc * 9 + 6] * t6 + wc[oc * 9 + 7] * t7 + wc[oc * 9 + 8] * t8;
        }
    }
#pragma unroll
    for (int oc = 0; oc < NOFF; oc++)
        atomicAdd(&tmp[((b * NOFF + oc) * Hx + y) * Wx + tid], acc[oc]);
}

// Per-(b,k) spatial softmax stats over HW: stats[bk*2]=max, stats[bk*2+1]=1/sum(exp(v-max))
__global__ __launch_bounds__(256) void k2_softmax(
        const float* __restrict__ tmp, float* __restrict__ stats) {
    int bk = blockIdx.x;              // 0..17
    int b = bk / Kx, k = bk % Kx;
    const float* p = tmp + ((b * NOFF) + 2 * Kx + k) * HWx;
    __shared__ float red[256];
    int tid = threadIdx.x;
    float mx = -1e30f;
    for (int i = tid; i < HWx; i += 256) mx = fmaxf(mx, p[i]);
    red[tid] = mx; __syncthreads();
    for (int s = 128; s > 0; s >>= 1) {
        if (tid < s) red[tid] = fmaxf(red[tid], red[tid + s]);
        __syncthreads();
    }
    mx = red[0]; __syncthreads();
    float sm = 0.f;
    for (int i = tid; i < HWx; i += 256) sm += __expf(p[i] - mx);
    red[tid] = sm; __syncthreads();
    for (int s = 128; s > 0; s >>= 1) {
        if (tid < s) red[tid] += red[tid + s];
        __syncthreads();
    }
    if (tid == 0) { stats[bk * 2] = mx; stats[bk * 2 + 1] = 1.f / red[0]; }
}

// Bilinear sample * softmax mask, summed over k -> agg[b,c,h,w].
// Thread = pixel; grid (HW/256, B, 4 c-chunks).
__global__ __launch_bounds__(256) void k3_sample(
        const float* __restrict__ x, const float* __restrict__ tmp,
        const float* __restrict__ stats, float* __restrict__ agg) {
    int tid = threadIdx.x;
    int hw  = blockIdx.x * 256 + tid;
    int b   = blockIdx.y;
    int c0  = blockIdx.z * 64;
    int y   = hw >> 7;
    int xx  = hw & (Wx - 1);

    float cw[Kx][4];
    int   co[Kx][4];
#pragma unroll
    for (int k = 0; k < Kx; k++) {
        float dy = tmp[((b * NOFF) + 2 * k) * HWx + hw];
        float dx = tmp[((b * NOFF) + 2 * k + 1) * HWx + hw];
        float lg = tmp[((b * NOFF) + 2 * Kx + k) * HWx + hw];
        float m  = __expf(lg - stats[(b * Kx + k) * 2]) * stats[(b * Kx + k) * 2 + 1];
        float py = dy + (float)(k / 3 - 1 + y);
        float px = dx + (float)(k % 3 - 1 + xx);
        float fy = floorf(py), fx = floorf(px);
        int y0 = (int)fy, x0 = (int)fx;
        float ly = py - fy, lx = px - fx;
        float w00 = (1.f - ly) * (1.f - lx) * m;
        float w01 = (1.f - ly) * lx * m;
        float w10 = ly * (1.f - lx) * m;
        float w11 = ly * lx * m;
        int y1 = y0 + 1, x1 = x0 + 1;
        bool vy0 = (y0 >= 0) & (y0 < Hx), vy1 = (y1 >= 0) & (y1 < Hx);
        bool vx0 = (x0 >= 0) & (x0 < Wx), vx1 = (x1 >= 0) & (x1 < Wx);
        int cy0 = min(max(y0, 0), Hx - 1), cy1 = min(max(y1, 0), Hx - 1);
        int cx0 = min(max(x0, 0), Wx - 1), cx1 = min(max(x1, 0), Wx - 1);
        cw[k][0] = (vy0 && vx0) ? w00 : 0.f;  co[k][0] = cy0 * Wx + cx0;
        cw[k][1] = (vy0 && vx1) ? w01 : 0.f;  co[k][1] = cy0 * Wx + cx1;
        cw[k][2] = (vy1 && vx0) ? w10 : 0.f;  co[k][2] = cy1 * Wx + cx0;
        cw[k][3] = (vy1 && vx1) ? w11 : 0.f;  co[k][3] = cy1 * Wx + cx1;
    }

    const float* xb = x + ((b * Cx) + c0) * HWx;
    float* ab = agg + ((b * Cx) + c0) * HWx + hw;
    for (int ci = 0; ci < 64; ci++) {
        float a = 0.f;
#pragma unroll
        for (int k = 0; k < Kx; k++) {
            a += cw[k][0] * xb[co[k][0]] + cw[k][1] * xb[co[k][1]]
               + cw[k][2] * xb[co[k][2]] + cw[k][3] * xb[co[k][3]];
        }
        *ab = a;
        xb += HWx; ab += HWx;
    }
}

// out[b,o,hw] = bias[o] + sum_c weight[o,c] * agg[b,c,hw]
// Tile 64(o) x 64(hw), 256 threads, 4x4 per thread, K-step 16.
__global__ __launch_bounds__(256) void k4_gemm(
        const float* __restrict__ agg, const float* __restrict__ weight,
        const float* __restrict__ bias, float* __restrict__ out) {
    int b  = blockIdx.z;
    int o0 = blockIdx.y * 64;
    int n0 = blockIdx.x * 64;
    __shared__ float At[16][64];      // [k][hw]
    __shared__ float Wt[16][68];      // [k][o], padded for alignment/banks
    int tid = threadIdx.x;
    int tx = tid & 15;                // hw quad
    int ty = tid >> 4;                // o quad
    float acc[4][4];
#pragma unroll
    for (int i = 0; i < 4; i++)
#pragma unroll
        for (int j = 0; j < 4; j++) acc[i][j] = 0.f;

    for (int k0 = 0; k0 < Cx; k0 += 16) {
        {
            int kk = tid >> 6;        // 0..3
            int j  = tid & 63;
#pragma unroll
            for (int r = 0; r < 4; r++)
                At[kk + 4 * r][j] = agg[((b * Cx) + k0 + kk + 4 * r) * HWx + n0 + j];
        }
        {
            int ki = tid & 15;
            int oi = tid >> 4;        // 0..15
#pragma unroll
            for (int r = 0; r < 4; r++)
                Wt[ki][oi + 16 * r] = weight[(o0 + oi + 16 * r) * Cx + k0 + ki];
        }
        __syncthreads();
#pragma unroll
        for (int k = 0; k < 16; k++) {
            float a[4], w[4];
#pragma unroll
            for (int j = 0; j < 4; j++) a[j] = At[k][4 * tx + j];
#pragma unroll
            for (int i = 0; i < 4; i++) w[i] = Wt[k][4 * ty + i];
#pragma unroll
            for (int i = 0; i < 4; i++)
#pragma unroll
                for (int j = 0; j < 4; j++) acc[i][j] += w[i] * a[j];
        }
        __syncthreads();
    }

#pragma unroll
    for (int i = 0; i < 4; i++) {
        int o = o0 + 4 * ty + i;
        float bo = bias[o];
#pragma unroll
        for (int j = 0; j < 4; j++)
            out[((b * Ox) + o) * HWx + n0 + 4 * tx + j] = acc[i][j] + bo;
    }
}

extern "C" void kernel_launch(void* const* d_in, const int* in_sizes, int n_in,
                              void* d_out, int out_size, void* d_ws, size_t ws_size,
                              hipStream_t stream) {
    const float* x      = (const float*)d_in[0];
    const float* w_off  = (const float*)d_in[1];
    const float* b_off  = (const float*)d_in[2];
    const float* weight = (const float*)d_in[3];
    const float* bias   = (const float*)d_in[4];
    float* out = (float*)d_out;
    float* ws  = (float*)d_ws;

    float* tmp   = ws;
    float* w_t   = ws + 884736;
    float* stats = ws + 946944;
    float* agg   = ws + 947008;

    k_zero<<<dim3((884736 + 255) / 256), 256, 0, stream>>>(tmp, 884736);
    k_wtr<<<dim3((NOFF * Cx * 9 + 255) / 256), 256, 0, stream>>>(w_off, w_t);
    k1_offconv<<<dim3(Hx, Bx, 4), 128, 0, stream>>>(x, w_t, b_off, tmp);
    k2_softmax<<<dim3(Bx * Kx), 256, 0, stream>>>(tmp, stats);
    k3_sample<<<dim3(HWx / 256, Bx, 4), 256, 0, stream>>>(x, tmp, stats, agg);
    k4_gemm<<<dim3(HWx / 64, Ox / 64, Bx), 256, 0, stream>>>(agg, weight, bias, out);
}

// Round 2
// 489.454 us; speedup vs baseline: 1.1735x; 1.1735x over previous
//
#include <hip/hip_runtime.h>

#define Bx 2
#define Cx 256
#define Hx 128
#define Wx 128
#define HWx (Hx*Wx)     // 16384
#define Ox 256
#define Kx 9
#define NOFF 27         // 3*K offset-conv output channels

// ws layout (float offsets):
//   tmp   [0, 884736)            B*27*HW
//   w_t   [884736, 946944)       27*256*9 transposed to [c][oc][t]
//   stats [946944, 947008)       18*2 (max, 1/sum) padded
//   agg   [947008, 947008+8388608)

// init tmp with bias (conv accumulates on top via atomics)
__global__ void k_init(const float* __restrict__ b_off, float* __restrict__ p, int n) {
    int i = blockIdx.x * 256 + threadIdx.x;
    if (i < n) p[i] = b_off[(i / HWx) % NOFF];
}

__global__ void k_wtr(const float* __restrict__ w_off, float* __restrict__ w_t) {
    int i = blockIdx.x * 256 + threadIdx.x;
    if (i >= NOFF * Cx * 9) return;
    int oc = i / (Cx * 9);
    int r  = i % (Cx * 9);
    int c  = r / 9;
    int t  = r % 9;
    w_t[(c * NOFF + oc) * 9 + t] = w_off[i];
}

// 3x3 conv C=256 -> 27, pad 1. Thread per pixel, 16 c-chunks of 16 channels.
// grid (HW/256, B, 16). Taps direct from global (L1-hot), weights scalar-loaded.
__global__ __launch_bounds__(256) void k1_offconv(
        const float* __restrict__ x, const float* __restrict__ w_t,
        float* __restrict__ tmp) {
    int tid = threadIdx.x;
    int hw  = blockIdx.x * 256 + tid;
    int b   = blockIdx.y;
    int cc  = blockIdx.z;             // 0..15
    int y   = hw >> 7;
    int xx  = hw & (Wx - 1);

    float acc[NOFF];
#pragma unroll
    for (int oc = 0; oc < NOFF; oc++) acc[oc] = 0.f;

    const float* xb = x + ((b * Cx) + cc * 16) * HWx;
    const float* wc = w_t + (cc * 16) * (NOFF * 9);

    for (int ci = 0; ci < 16; ci++) {
        float t[9];
#pragma unroll
        for (int dy = -1; dy <= 1; dy++) {
            int yy = y + dy;
            bool vy = (yy >= 0) & (yy < Hx);
            int cy = min(max(yy, 0), Hx - 1);
#pragma unroll
            for (int dx = -1; dx <= 1; dx++) {
                int xq = xx + dx;
                bool v = vy & (xq >= 0) & (xq < Wx);
                int cx = min(max(xq, 0), Wx - 1);
                float val = xb[cy * Wx + cx];
                t[(dy + 1) * 3 + (dx + 1)] = v ? val : 0.f;
            }
        }
#pragma unroll
        for (int oc = 0; oc < NOFF; oc++) {
            acc[oc] += wc[oc * 9 + 0] * t[0] + wc[oc * 9 + 1] * t[1] + wc[oc * 9 + 2] * t[2]
                     + wc[oc * 9 + 3] * t[3] + wc[oc * 9 + 4] * t[4] + wc[oc * 9 + 5] * t[5]
                     + wc[oc * 9 + 6] * t[6] + wc[oc * 9 + 7] * t[7] + wc[oc * 9 + 8] * t[8];
        }
        xb += HWx;
        wc += NOFF * 9;
    }
#pragma unroll
    for (int oc = 0; oc < NOFF; oc++)
        atomicAdd(&tmp[((b * NOFF + oc) * HWx) + hw], acc[oc]);
}

// Per-(b,k) spatial softmax stats over HW: stats[bk*2]=max, stats[bk*2+1]=1/sum(exp(v-max))
__global__ __launch_bounds__(256) void k2_softmax(
        const float* __restrict__ tmp, float* __restrict__ stats) {
    int bk = blockIdx.x;              // 0..17
    int b = bk / Kx, k = bk % Kx;
    const float* p = tmp + ((b * NOFF) + 2 * Kx + k) * HWx;
    __shared__ float red[256];
    int tid = threadIdx.x;
    float mx = -1e30f;
    for (int i = tid; i < HWx; i += 256) mx = fmaxf(mx, p[i]);
    red[tid] = mx; __syncthreads();
    for (int s = 128; s > 0; s >>= 1) {
        if (tid < s) red[tid] = fmaxf(red[tid], red[tid + s]);
        __syncthreads();
    }
    mx = red[0]; __syncthreads();
    float sm = 0.f;
    for (int i = tid; i < HWx; i += 256) sm += __expf(p[i] - mx);
    red[tid] = sm; __syncthreads();
    for (int s = 128; s > 0; s >>= 1) {
        if (tid < s) red[tid] += red[tid + s];
        __syncthreads();
    }
    if (tid == 0) { stats[bk * 2] = mx; stats[bk * 2 + 1] = 1.f / red[0]; }
}

// Bilinear sample * softmax mask, summed over k -> agg[b,c,h,w].
// Thread = pixel; grid (HW/256, B, 16 c-chunks of 16).
__global__ __launch_bounds__(256) void k3_sample(
        const float* __restrict__ x, const float* __restrict__ tmp,
        const float* __restrict__ stats, float* __restrict__ agg) {
    int tid = threadIdx.x;
    int hw  = blockIdx.x * 256 + tid;
    int b   = blockIdx.y;
    int c0  = blockIdx.z * 16;
    int y   = hw >> 7;
    int xx  = hw & (Wx - 1);

    float cw[Kx][4];
    int   co[Kx][4];
#pragma unroll
    for (int k = 0; k < Kx; k++) {
        float dy = tmp[((b * NOFF) + 2 * k) * HWx + hw];
        float dx = tmp[((b * NOFF) + 2 * k + 1) * HWx + hw];
        float lg = tmp[((b * NOFF) + 2 * Kx + k) * HWx + hw];
        float m  = __expf(lg - stats[(b * Kx + k) * 2]) * stats[(b * Kx + k) * 2 + 1];
        float py = dy + (float)(k / 3 - 1 + y);
        float px = dx + (float)(k % 3 - 1 + xx);
        float fy = floorf(py), fx = floorf(px);
        int y0 = (int)fy, x0 = (int)fx;
        float ly = py - fy, lx = px - fx;
        float w00 = (1.f - ly) * (1.f - lx) * m;
        float w01 = (1.f - ly) * lx * m;
        float w10 = ly * (1.f - lx) * m;
        float w11 = ly * lx * m;
        int y1 = y0 + 1, x1 = x0 + 1;
        bool vy0 = (y0 >= 0) & (y0 < Hx), vy1 = (y1 >= 0) & (y1 < Hx);
        bool vx0 = (x0 >= 0) & (x0 < Wx), vx1 = (x1 >= 0) & (x1 < Wx);
        int cy0 = min(max(y0, 0), Hx - 1), cy1 = min(max(y1, 0), Hx - 1);
        int cx0 = min(max(x0, 0), Wx - 1), cx1 = min(max(x1, 0), Wx - 1);
        cw[k][0] = (vy0 && vx0) ? w00 : 0.f;  co[k][0] = cy0 * Wx + cx0;
        cw[k][1] = (vy0 && vx1) ? w01 : 0.f;  co[k][1] = cy0 * Wx + cx1;
        cw[k][2] = (vy1 && vx0) ? w10 : 0.f;  co[k][2] = cy1 * Wx + cx0;
        cw[k][3] = (vy1 && vx1) ? w11 : 0.f;  co[k][3] = cy1 * Wx + cx1;
    }

    const float* xb = x + ((b * Cx) + c0) * HWx;
    float* ab = agg + ((b * Cx) + c0) * HWx + hw;
#pragma unroll 2
    for (int ci = 0; ci < 16; ci++) {
        float a = 0.f;
#pragma unroll
        for (int k = 0; k < Kx; k++) {
            a += cw[k][0] * xb[co[k][0]] + cw[k][1] * xb[co[k][1]]
               + cw[k][2] * xb[co[k][2]] + cw[k][3] * xb[co[k][3]];
        }
        *ab = a;
        xb += HWx; ab += HWx;
    }
}

// out[b,o,hw] = bias[o] + sum_c weight[o,c] * agg[b,c,hw]
// Tile 64(o) x 64(hw), 256 threads, 4x4 per thread, K-step 16.
__global__ __launch_bounds__(256) void k4_gemm(
        const float* __restrict__ agg, const float* __restrict__ weight,
        const float* __restrict__ bias, float* __restrict__ out) {
    int b  = blockIdx.z;
    int o0 = blockIdx.y * 64;
    int n0 = blockIdx.x * 64;
    __shared__ float At[16][64];      // [k][hw]
    __shared__ float Wt[16][68];      // [k][o], padded for alignment/banks
    int tid = threadIdx.x;
    int tx = tid & 15;                // hw quad
    int ty = tid >> 4;                // o quad
    float acc[4][4];
#pragma unroll
    for (int i = 0; i < 4; i++)
#pragma unroll
        for (int j = 0; j < 4; j++) acc[i][j] = 0.f;

    for (int k0 = 0; k0 < Cx; k0 += 16) {
        {
            int kk = tid >> 6;        // 0..3
            int j  = tid & 63;
#pragma unroll
            for (int r = 0; r < 4; r++)
                At[kk + 4 * r][j] = agg[((b * Cx) + k0 + kk + 4 * r) * HWx + n0 + j];
        }
        {
            int ki = tid & 15;
            int oi = tid >> 4;        // 0..15
#pragma unroll
            for (int r = 0; r < 4; r++)
                Wt[ki][oi + 16 * r] = weight[(o0 + oi + 16 * r) * Cx + k0 + ki];
        }
        __syncthreads();
#pragma unroll
        for (int k = 0; k < 16; k++) {
            float a[4], w[4];
#pragma unroll
            for (int j = 0; j < 4; j++) a[j] = At[k][4 * tx + j];
#pragma unroll
            for (int i = 0; i < 4; i++) w[i] = Wt[k][4 * ty + i];
#pragma unroll
            for (int i = 0; i < 4; i++)
#pragma unroll
                for (int j = 0; j < 4; j++) acc[i][j] += w[i] * a[j];
        }
        __syncthreads();
    }

#pragma unroll
    for (int i = 0; i < 4; i++) {
        int o = o0 + 4 * ty + i;
        float bo = bias[o];
#pragma unroll
        for (int j = 0; j < 4; j++)
            out[((b * Ox) + o) * HWx + n0 + 4 * tx + j] = acc[i][j] + bo;
    }
}

extern "C" void kernel_launch(void* const* d_in, const int* in_sizes, int n_in,
                              void* d_out, int out_size, void* d_ws, size_t ws_size,
                              hipStream_t stream) {
    const float* x      = (const float*)d_in[0];
    const float* w_off  = (const float*)d_in[1];
    const float* b_off  = (const float*)d_in[2];
    const float* weight = (const float*)d_in[3];
    const float* bias   = (const float*)d_in[4];
    float* out = (float*)d_out;
    float* ws  = (float*)d_ws;

    float* tmp   = ws;
    float* w_t   = ws + 884736;
    float* stats = ws + 946944;
    float* agg   = ws + 947008;

    k_init<<<dim3((884736 + 255) / 256), 256, 0, stream>>>(b_off, tmp, 884736);
    k_wtr<<<dim3((NOFF * Cx * 9 + 255) / 256), 256, 0, stream>>>(w_off, w_t);
    k1_offconv<<<dim3(HWx / 256, Bx, 16), 256, 0, stream>>>(x, w_t, tmp);
    k2_softmax<<<dim3(Bx * Kx), 256, 0, stream>>>(tmp, stats);
    k3_sample<<<dim3(HWx / 256, Bx, 16), 256, 0, stream>>>(x, tmp, stats, agg);
    k4_gemm<<<dim3(HWx / 64, Ox / 64, Bx), 256, 0, stream>>>(agg, weight, bias, out);
}